// Round 1
// baseline (1104.846 us; speedup 1.0000x reference)
//
#include <hip/hip_runtime.h>
#include <math.h>

#define HH 512
#define WW 512
#define TT 5
#define CC 5
#define TH 16
#define TW 32
#define LDS_R (TH + 2)   // 18
#define LDS_C (TW + 2)   // 34
#define LDS_N (TT * CC * LDS_R * LDS_C)  // 15300 floats = 61.2 KB

__device__ __forceinline__ float fast_sigmoid(float x) {
    return __builtin_amdgcn_rcpf(1.0f + __expf(-x));
}

extern "C" __global__ __launch_bounds__(512)
void conv_ltc_kernel(const float* __restrict__ x, const float* __restrict__ cw,
                     const float* __restrict__ gamma, const float* __restrict__ beta,
                     const float* __restrict__ cm, const float* __restrict__ vleak,
                     const float* __restrict__ tau, const float* __restrict__ erev,
                     float* __restrict__ out)
{
    __shared__ float lds[LDS_N];

    const int tid = threadIdx.x;
    const int bx = blockIdx.x;   // col tile
    const int by = blockIdx.y;   // row tile
    const int b  = blockIdx.z;   // batch

    const size_t xbase = (size_t)b * (TT * CC * HH * WW);

    // ---- stage x[b, :, :, tile+halo] into LDS (zero-padded borders) ----
    for (int idx = tid; idx < LDS_N; idx += 512) {
        int cc  = idx % LDS_C;
        int tmp = idx / LDS_C;
        int r   = tmp % LDS_R;
        int tc  = tmp / LDS_R;          // t*CC + ic, 0..24
        int gr = by * TH + r - 1;
        int gc = bx * TW + cc - 1;
        float v = 0.0f;
        if ((unsigned)gr < HH && (unsigned)gc < WW)
            v = x[xbase + (size_t)tc * (HH * WW) + (size_t)gr * WW + gc];
        lds[idx] = v;
    }
    __syncthreads();

    const int tx = tid & 31;     // col in tile
    const int ty = tid >> 5;     // row in tile

    float acc[TT][CC];
    #pragma unroll
    for (int t = 0; t < TT; ++t)
        #pragma unroll
        for (int o = 0; o < CC; ++o) acc[t][o] = 0.0f;

    // ---- conv accumulation: all 5 timesteps share each weight load ----
    for (int ic = 0; ic < CC; ++ic) {
        float xv[TT][9];
        #pragma unroll
        for (int t = 0; t < TT; ++t) {
            #pragma unroll
            for (int dr = 0; dr < 3; ++dr) {
                const float* lp = &lds[((t * CC + ic) * LDS_R + ty + dr) * LDS_C + tx];
                xv[t][dr * 3 + 0] = lp[0];
                xv[t][dr * 3 + 1] = lp[1];
                xv[t][dr * 3 + 2] = lp[2];
            }
        }
        #pragma unroll
        for (int oc = 0; oc < CC; ++oc) {
            const float* wp = cw + (oc * CC + ic) * 9;   // uniform -> s_load
            float wv[9];
            #pragma unroll
            for (int k = 0; k < 9; ++k) wv[k] = wp[k];
            #pragma unroll
            for (int t = 0; t < TT; ++t) {
                float a = acc[t][oc];
                #pragma unroll
                for (int k = 0; k < 9; ++k) a = fmaf(wv[k], xv[t][k], a);
                acc[t][oc] = a;
            }
        }
    }

    // ---- per-channel params (uniform -> SGPR) ----
    float g[CC], be[CC], cmv[CC], vl[CC], tm[CC], er[CC];
    #pragma unroll
    for (int o = 0; o < CC; ++o) {
        g[o] = gamma[o]; be[o] = beta[o]; cmv[o] = cm[o];
        vl[o] = vleak[o]; tm[o] = tau[o]; er[o] = erev[o];
    }

    const int gr = by * TH + ty;
    const int gc = bx * TW + tx;
    const size_t obase = (size_t)gr * WW + gc;

    // ---- LTC recurrence over T, in-register ----
    float vpre[CC];
    #pragma unroll
    for (int o = 0; o < CC; ++o) vpre[o] = 0.0f;

    #pragma unroll
    for (int t = 0; t < TT; ++t) {
        #pragma unroll
        for (int o = 0; o < CC; ++o) {
            float wih = fmaf(acc[t][o], g[o], be[o]);       // BN fold
            float sg  = fast_sigmoid(wih);
            float den = fmaf(cmv[o], sg, vl[o]);
            float num = fmaf(tm[o] * vpre[o], __builtin_amdgcn_rcpf(den), wih * er[o]);
            float v   = fast_sigmoid(num);                  // /(1+1e-8) == 1.0f in f32
            vpre[o] = v;
            out[((size_t)((b * TT + t) * CC + o)) * (HH * WW) + obase] = v;
        }
    }
}

extern "C" __global__ __launch_bounds__(256)
void head_decode_kernel(const float* __restrict__ y, const float* __restrict__ w,
                        const float* __restrict__ bias, float* __restrict__ det,
                        int Cin, int f, float s, int row_off,
                        float a0w, float a0h, float a1w, float a1h, float a2w, float a2h)
{
    const int b   = blockIdx.y;
    const int pix = blockIdx.x * 256 + threadIdx.x;
    const int n   = f * f;
    if (pix >= n) return;
    const int hy = pix / f;
    const int hx = pix - hy * f;

    float acc[21];
    #pragma unroll
    for (int o = 0; o < 21; ++o) acc[o] = bias[o];

    const float* yb = y + (size_t)b * Cin * n + pix;
    for (int c = 0; c < Cin; ++c) {
        float v = yb[(size_t)c * n];       // coalesced across threads
        const float* wc = w + c;           // uniform -> s_load
        #pragma unroll
        for (int o = 0; o < 21; ++o) acc[o] = fmaf(v, wc[o * Cin], acc[o]);
    }

    const float aw[3] = {a0w, a1w, a2w};
    const float ah[3] = {a0h, a1h, a2h};
    const float inv = 1.0f / 512.0f;

    #pragma unroll
    for (int a = 0; a < 3; ++a) {
        int r = row_off + pix * 3 + a;
        float* dp = det + ((size_t)b * 16128 + r) * 7;
        dp[0] = acc[a];                       // obj
        dp[1] = acc[3 + a * 2];               // cls0
        dp[2] = acc[4 + a * 2];               // cls1
        float txv = acc[9  + a * 4];
        float tyv = acc[10 + a * 4];
        float twv = acc[11 + a * 4];
        float thv = acc[12 + a * 4];
        float cx = (fast_sigmoid(txv) + (float)hx) * s;
        float cy = (fast_sigmoid(tyv) + (float)hy) * s;
        float bw = __expf(twv) * aw[a];
        float bh = __expf(thv) * ah[a];
        dp[3] = (cx - bw * 0.5f) * inv;
        dp[4] = (cy - bh * 0.5f) * inv;
        dp[5] = (cx + bw * 0.5f) * inv;
        dp[6] = (cy + bh * 0.5f) * inv;
    }
}

extern "C" void kernel_launch(void* const* d_in, const int* in_sizes, int n_in,
                              void* d_out, int out_size, void* d_ws, size_t ws_size,
                              hipStream_t stream)
{
    const float* x     = (const float*)d_in[0];
    const float* y1    = (const float*)d_in[1];   // [8,768,16,16]
    const float* y2    = (const float*)d_in[2];   // [8,384,32,32]
    const float* y3    = (const float*)d_in[3];   // [8,192,64,64]
    const float* cw    = (const float*)d_in[4];
    const float* gamma = (const float*)d_in[5];
    const float* beta  = (const float*)d_in[6];
    const float* cm    = (const float*)d_in[7];
    const float* vleak = (const float*)d_in[8];
    const float* tau   = (const float*)d_in[9];
    const float* erev  = (const float*)d_in[10];
    const float* w1    = (const float*)d_in[11];
    const float* b1    = (const float*)d_in[12];
    const float* w2    = (const float*)d_in[13];
    const float* b2    = (const float*)d_in[14];
    const float* w3    = (const float*)d_in[15];
    const float* b3    = (const float*)d_in[16];

    float* out = (float*)d_out;
    float* det = out + (size_t)8 * 5 * 5 * 512 * 512;   // 52,428,800

    dim3 grid(WW / TW, HH / TH, 8);
    conv_ltc_kernel<<<grid, 512, 0, stream>>>(x, cw, gamma, beta, cm, vleak, tau, erev, out);

    // scale 0: stride 8,  f=64, y3/w3, rows [0, 12288)
    head_decode_kernel<<<dim3(16, 8), 256, 0, stream>>>(y3, w3, b3, det, 192, 64, 8.0f, 0,
                                                        10.f, 13.f, 16.f, 30.f, 33.f, 23.f);
    // scale 1: stride 16, f=32, y2/w2, rows [12288, 15360)
    head_decode_kernel<<<dim3(4, 8), 256, 0, stream>>>(y2, w2, b2, det, 384, 32, 16.0f, 12288,
                                                       30.f, 61.f, 62.f, 45.f, 59.f, 119.f);
    // scale 2: stride 32, f=16, y1/w1, rows [15360, 16128)
    head_decode_kernel<<<dim3(1, 8), 256, 0, stream>>>(y1, w1, b1, det, 768, 16, 32.0f, 15360,
                                                       116.f, 90.f, 156.f, 198.f, 373.f, 326.f);
}

// Round 2
// 324.020 us; speedup vs baseline: 3.4098x; 3.4098x over previous
//
#include <hip/hip_runtime.h>
#include <math.h>

#define HH 512
#define WW 512
#define TT 5
#define CC 5

// ---------------- conv+LTC: 64x16 tile, per-timestep LDS staging ----------------
#define CTW 64
#define CTH 16
#define LR (CTH + 2)          // 18
#define LC (CTW + 2)          // 66
#define STAGE_N (CC * LR * LC)  // 5940 floats = 23.76 KB

__device__ __forceinline__ float fast_sigmoid(float x) {
    return __builtin_amdgcn_rcpf(1.0f + __expf(-x));
}

extern "C" __global__ __launch_bounds__(512)
void conv_ltc_kernel(const float* __restrict__ x, const float* __restrict__ cw,
                     const float* __restrict__ gamma, const float* __restrict__ beta,
                     const float* __restrict__ cm, const float* __restrict__ vleak,
                     const float* __restrict__ tau, const float* __restrict__ erev,
                     float* __restrict__ out)
{
    __shared__ float xs[STAGE_N];

    const int tid = threadIdx.x;
    const int bx = blockIdx.x;   // col tile (0..7)
    const int by = blockIdx.y;   // row tile (0..31)
    const int b  = blockIdx.z;   // batch

    const int tx  = tid & 63;          // col 0..63
    const int tyy = tid >> 6;          // 0..7 -> rows tyy*2, tyy*2+1
    const int r0  = tyy * 2;

    // per-channel params (wave-uniform -> SGPR)
    float g[CC], be[CC], cmv[CC], vl[CC], tm[CC], er[CC];
    #pragma unroll
    for (int o = 0; o < CC; ++o) {
        g[o] = gamma[o]; be[o] = beta[o]; cmv[o] = cm[o];
        vl[o] = vleak[o]; tm[o] = tau[o]; er[o] = erev[o];
    }

    const size_t xb = (size_t)b * (TT * CC * HH * WW);
    const int grow0 = by * CTH;
    const int gcol0 = bx * CTW;

    float vpre[2][CC];
    #pragma unroll
    for (int r = 0; r < 2; ++r)
        #pragma unroll
        for (int o = 0; o < CC; ++o) vpre[r][o] = 0.0f;

    for (int t = 0; t < TT; ++t) {
        // ---- stage x[b,t,:, tile+halo] ----
        for (int i = tid; i < STAGE_N; i += 512) {
            int c2   = i % LC;
            int rest = i / LC;
            int rr   = rest % LR;
            int ch   = rest / LR;
            int gr = grow0 + rr - 1;
            int gc = gcol0 + c2 - 1;
            float v = 0.0f;
            if ((unsigned)gr < HH && (unsigned)gc < WW)
                v = x[xb + ((size_t)(t * CC + ch)) * (HH * WW) + (size_t)gr * WW + gc];
            xs[i] = v;
        }
        __syncthreads();

        float acc[2][CC];
        #pragma unroll
        for (int r = 0; r < 2; ++r)
            #pragma unroll
            for (int o = 0; o < CC; ++o) acc[r][o] = 0.0f;

        #pragma unroll
        for (int ic = 0; ic < CC; ++ic) {
            // 4 LDS rows x 3 cols covers the two vertical output pixels
            float rv[4][3];
            #pragma unroll
            for (int dr = 0; dr < 4; ++dr) {
                const float* lp = &xs[(ic * LR + (r0 + dr)) * LC + tx];
                rv[dr][0] = lp[0]; rv[dr][1] = lp[1]; rv[dr][2] = lp[2];
            }
            #pragma unroll
            for (int oc = 0; oc < CC; ++oc) {
                const float* wp = cw + (oc * CC + ic) * 9;   // uniform -> s_load
                float wv[9];
                #pragma unroll
                for (int k = 0; k < 9; ++k) wv[k] = wp[k];
                float a0 = acc[0][oc], a1 = acc[1][oc];
                #pragma unroll
                for (int dr = 0; dr < 3; ++dr)
                    #pragma unroll
                    for (int dc = 0; dc < 3; ++dc) {
                        a0 = fmaf(wv[dr * 3 + dc], rv[dr][dc],     a0);
                        a1 = fmaf(wv[dr * 3 + dc], rv[dr + 1][dc], a1);
                    }
                acc[0][oc] = a0; acc[1][oc] = a1;
            }
        }

        // ---- LTC update + store (2 rows) ----
        #pragma unroll
        for (int r = 0; r < 2; ++r) {
            const int grow = grow0 + r0 + r;
            const size_t ob = (size_t)grow * WW + gcol0 + tx;
            #pragma unroll
            for (int o = 0; o < CC; ++o) {
                float wih = fmaf(acc[r][o], g[o], be[o]);
                float sg  = fast_sigmoid(wih);
                float den = fmaf(cmv[o], sg, vl[o]);
                float num = fmaf(tm[o] * vpre[r][o], __builtin_amdgcn_rcpf(den), wih * er[o]);
                float v   = fast_sigmoid(num);
                vpre[r][o] = v;
                out[((size_t)((b * TT + t) * CC + o)) * (HH * WW) + ob] = v;
            }
        }
        __syncthreads();   // before next t overwrites xs
    }
}

// ---------------- fused detection head + decode, all 3 scales ----------------
// blocks: scale0 (y3, Cin=192, f=64): 512 | scale1 (y2, 384, 32): 128 | scale2 (y1, 768, 16): 32
#define SMEM_F 18432   // max(768*24, 512*21)

extern "C" __global__ __launch_bounds__(512)
void head_fused_kernel(const float* __restrict__ y3, const float* __restrict__ w3, const float* __restrict__ b3,
                       const float* __restrict__ y2, const float* __restrict__ w2, const float* __restrict__ b2,
                       const float* __restrict__ y1, const float* __restrict__ w1, const float* __restrict__ b1,
                       float* __restrict__ det)
{
    __shared__ float smem[SMEM_F];

    const int bid = blockIdx.x;
    const float *y, *w, *bias;
    int Cin, f, lgf, lgchunks, row_off;
    float s;
    float aw0, aw1, aw2, ah0, ah1, ah2;
    int sb;

    if (bid < 512) {
        sb = bid;       y = y3; w = w3; bias = b3; Cin = 192; f = 64; lgf = 6; lgchunks = 6; s = 8.0f;  row_off = 0;
        aw0 = 10.f;  ah0 = 13.f;  aw1 = 16.f;  ah1 = 30.f;  aw2 = 33.f;  ah2 = 23.f;
    } else if (bid < 640) {
        sb = bid - 512; y = y2; w = w2; bias = b2; Cin = 384; f = 32; lgf = 5; lgchunks = 4; s = 16.0f; row_off = 12288;
        aw0 = 30.f;  ah0 = 61.f;  aw1 = 62.f;  ah1 = 45.f;  aw2 = 59.f;  ah2 = 119.f;
    } else {
        sb = bid - 640; y = y1; w = w1; bias = b1; Cin = 768; f = 16; lgf = 4; lgchunks = 2; s = 32.0f; row_off = 15360;
        aw0 = 116.f; ah0 = 90.f;  aw1 = 156.f; ah1 = 198.f; aw2 = 373.f; ah2 = 326.f;
    }

    const int n     = f * f;
    const int b     = sb >> lgchunks;
    const int chunk = sb & ((1 << lgchunks) - 1);

    const int tid  = threadIdx.x;
    const int lane = tid & 63;
    const int grp  = tid >> 6;          // 0..7

    // ---- stage wT (padded rows of 24) into LDS ----
    const int wtot = Cin * 21;
    for (int i = tid; i < wtot; i += 512) {
        int o = i / Cin;
        int c = i - o * Cin;
        smem[c * 24 + o] = w[i];
    }
    __syncthreads();

    const int G   = Cin >> 3;
    const int pix = (chunk << 6) + lane;

    float acc[21];
    #pragma unroll
    for (int o = 0; o < 21; ++o) acc[o] = 0.0f;

    const float* yp = y + ((size_t)b * Cin + (size_t)grp * G) * n + pix;
    const int wbase = grp * G * 24;

    #pragma unroll 4
    for (int c = 0; c < G; ++c) {
        float v = yp[(size_t)c * n];                     // coalesced
        const float* wr = &smem[wbase + c * 24];         // wave-uniform -> broadcast
        float4 q0 = *(const float4*)(wr);
        float4 q1 = *(const float4*)(wr + 4);
        float4 q2 = *(const float4*)(wr + 8);
        float4 q3 = *(const float4*)(wr + 12);
        float4 q4 = *(const float4*)(wr + 16);
        float  s20 = wr[20];
        float wv[21] = {q0.x,q0.y,q0.z,q0.w, q1.x,q1.y,q1.z,q1.w,
                        q2.x,q2.y,q2.z,q2.w, q3.x,q3.y,q3.z,q3.w,
                        q4.x,q4.y,q4.z,q4.w, s20};
        #pragma unroll
        for (int o = 0; o < 21; ++o) acc[o] = fmaf(v, wv[o], acc[o]);
    }
    __syncthreads();   // all reads of wT done; smem reused for reduction

    #pragma unroll
    for (int o = 0; o < 21; ++o) smem[tid * 21 + o] = acc[o];
    __syncthreads();

    if (tid < 64) {
        float r[21];
        #pragma unroll
        for (int o = 0; o < 21; ++o) r[o] = bias[o];
        #pragma unroll
        for (int g2 = 0; g2 < 8; ++g2) {
            const float* rp = &smem[(g2 * 64 + lane) * 21];
            #pragma unroll
            for (int o = 0; o < 21; ++o) r[o] += rp[o];
        }

        const int hy = pix >> lgf;
        const int hx = pix & (f - 1);
        const float inv = 1.0f / 512.0f;
        const float AW[3] = {aw0, aw1, aw2};
        const float AH[3] = {ah0, ah1, ah2};

        #pragma unroll
        for (int a = 0; a < 3; ++a) {
            const int row = row_off + pix * 3 + a;
            float* dp = det + ((size_t)b * 16128 + row) * 7;
            dp[0] = r[a];
            dp[1] = r[3 + a * 2];
            dp[2] = r[4 + a * 2];
            float txv = r[9  + a * 4];
            float tyv = r[10 + a * 4];
            float twv = r[11 + a * 4];
            float thv = r[12 + a * 4];
            float cx = (fast_sigmoid(txv) + (float)hx) * s;
            float cy = (fast_sigmoid(tyv) + (float)hy) * s;
            float bw = __expf(twv) * AW[a];
            float bh = __expf(thv) * AH[a];
            dp[3] = (cx - bw * 0.5f) * inv;
            dp[4] = (cy - bh * 0.5f) * inv;
            dp[5] = (cx + bw * 0.5f) * inv;
            dp[6] = (cy + bh * 0.5f) * inv;
        }
    }
}

extern "C" void kernel_launch(void* const* d_in, const int* in_sizes, int n_in,
                              void* d_out, int out_size, void* d_ws, size_t ws_size,
                              hipStream_t stream)
{
    const float* x     = (const float*)d_in[0];
    const float* y1    = (const float*)d_in[1];   // [8,768,16,16]
    const float* y2    = (const float*)d_in[2];   // [8,384,32,32]
    const float* y3    = (const float*)d_in[3];   // [8,192,64,64]
    const float* cw    = (const float*)d_in[4];
    const float* gamma = (const float*)d_in[5];
    const float* beta  = (const float*)d_in[6];
    const float* cm    = (const float*)d_in[7];
    const float* vleak = (const float*)d_in[8];
    const float* tau   = (const float*)d_in[9];
    const float* erev  = (const float*)d_in[10];
    const float* w1    = (const float*)d_in[11];
    const float* b1    = (const float*)d_in[12];
    const float* w2    = (const float*)d_in[13];
    const float* b2    = (const float*)d_in[14];
    const float* w3    = (const float*)d_in[15];
    const float* b3    = (const float*)d_in[16];

    float* out = (float*)d_out;
    float* det = out + (size_t)8 * 5 * 5 * 512 * 512;   // 52,428,800

    dim3 cgrid(WW / CTW, HH / CTH, 8);     // 8 x 32 x 8
    conv_ltc_kernel<<<cgrid, 512, 0, stream>>>(x, cw, gamma, beta, cm, vleak, tau, erev, out);

    head_fused_kernel<<<dim3(672), 512, 0, stream>>>(y3, w3, b3, y2, w2, b2, y1, w1, b1, det);
}

// Round 3
// 201.861 us; speedup vs baseline: 5.4733x; 1.6052x over previous
//
#include <hip/hip_runtime.h>
#include <math.h>

#define HH 512
#define WW 512
#define HWp (HH * WW)
#define TT 5
#define CC 5

// ---------------- conv+LTC: 64x16 tile, float4-granule staging, T14 split ----------------
#define CTW 64
#define CTH 16
#define NROW 18              // CTH + 2 halo rows
#define LCP 72               // padded row: 18 float4 granules, covers cols [gcol0-4, gcol0+68)
#define LDSF (CC * NROW * LCP)   // 6480 floats = 25.92 KB
#define NG (CC * NROW * 18)      // 1620 16B granules

__device__ __forceinline__ float fast_sigmoid(float x) {
    return __builtin_amdgcn_rcpf(1.0f + __expf(-x));
}

extern "C" __global__ __launch_bounds__(512)
void conv_ltc_kernel(const float* __restrict__ x, const float* __restrict__ cw,
                     const float* __restrict__ gamma, const float* __restrict__ beta,
                     const float* __restrict__ cm, const float* __restrict__ vleak,
                     const float* __restrict__ tau, const float* __restrict__ erev,
                     float* __restrict__ out)
{
    __shared__ float xs[LDSF];

    const int tid = threadIdx.x;
    const int bx = blockIdx.x;   // col tile (0..7)
    const int by = blockIdx.y;   // row tile (0..31)
    const int b  = blockIdx.z;   // batch

    const int grow0 = by * CTH;
    const int gcol0 = bx * CTW;
    const size_t xb = (size_t)b * (TT * CC * HWp);

    // ---- per-thread staging meta, computed ONCE ----
    int goff[4];   // element offset into x[b,t,...] plane set, or -1 => fill zeros
    int lofs[4];   // float index into xs, or -1 => skip store
    #pragma unroll
    for (int k = 0; k < 4; ++k) {
        int g = tid + k * 512;
        bool valid = g < NG;
        int gg  = valid ? g : 0;
        int ch  = gg / 324;            // 18 rows * 18 granule-cols
        int rem = gg - ch * 324;
        int row = rem / 18;
        int c4  = rem - row * 18;
        int gr = grow0 + row - 1;
        int gc = gcol0 - 4 + c4 * 4;
        bool pred = valid && ((unsigned)gr < (unsigned)HH) && ((unsigned)gc < (unsigned)WW);
        goff[k] = pred ? (ch * HWp + gr * WW + gc) : -1;
        lofs[k] = valid ? ((ch * NROW + row) * LCP + c4 * 4) : -1;
    }

    // per-channel params (wave-uniform -> SGPR)
    float g_[CC], be[CC], cmv[CC], vl[CC], tm[CC], er[CC];
    #pragma unroll
    for (int o = 0; o < CC; ++o) {
        g_[o] = gamma[o]; be[o] = beta[o]; cmv[o] = cm[o];
        vl[o] = vleak[o]; tm[o] = tau[o]; er[o] = erev[o];
    }

    const int tx = tid & 63;          // col 0..63
    const int r0 = (tid >> 6) * 2;    // rows r0, r0+1

    auto stage_load = [&](int t, float4* vb) {
        const float* xt = x + xb + (size_t)t * (CC * HWp);
        #pragma unroll
        for (int k = 0; k < 4; ++k) {
            float4 v = make_float4(0.f, 0.f, 0.f, 0.f);
            if (goff[k] >= 0) v = *(const float4*)(xt + goff[k]);
            vb[k] = v;
        }
    };
    auto stage_write = [&](const float4* vb) {
        #pragma unroll
        for (int k = 0; k < 4; ++k)
            if (lofs[k] >= 0) *(float4*)&xs[lofs[k]] = vb[k];
    };

    // ---- prologue: stage t=0 ----
    {
        float4 vb[4];
        stage_load(0, vb);
        stage_write(vb);
    }
    __syncthreads();

    float vpre[2][CC];
    #pragma unroll
    for (int r = 0; r < 2; ++r)
        #pragma unroll
        for (int o = 0; o < CC; ++o) vpre[r][o] = 0.0f;

    for (int t = 0; t < TT; ++t) {
        // issue next-t loads early; they fly under this t's compute
        float4 vb[4];
        if (t < TT - 1) stage_load(t + 1, vb);

        float acc[2][CC];
        #pragma unroll
        for (int r = 0; r < 2; ++r)
            #pragma unroll
            for (int o = 0; o < CC; ++o) acc[r][o] = 0.0f;

        #pragma unroll
        for (int ic = 0; ic < CC; ++ic) {
            float rv[4][3];
            #pragma unroll
            for (int dr = 0; dr < 4; ++dr) {
                const float* lp = &xs[(ic * NROW + (r0 + dr)) * LCP + tx + 3];
                rv[dr][0] = lp[0]; rv[dr][1] = lp[1]; rv[dr][2] = lp[2];
            }
            #pragma unroll
            for (int oc = 0; oc < CC; ++oc) {
                const float* wp = cw + (oc * CC + ic) * 9;   // uniform -> s_load
                float wv[9];
                #pragma unroll
                for (int k = 0; k < 9; ++k) wv[k] = wp[k];
                float a0 = acc[0][oc], a1 = acc[1][oc];
                #pragma unroll
                for (int dr = 0; dr < 3; ++dr)
                    #pragma unroll
                    for (int dc = 0; dc < 3; ++dc) {
                        a0 = fmaf(wv[dr * 3 + dc], rv[dr][dc],     a0);
                        a1 = fmaf(wv[dr * 3 + dc], rv[dr + 1][dc], a1);
                    }
                acc[0][oc] = a0; acc[1][oc] = a1;
            }
        }

        // ---- LTC update + store (2 rows) ----
        #pragma unroll
        for (int r = 0; r < 2; ++r) {
            const int grow = grow0 + r0 + r;
            const size_t ob = (size_t)grow * WW + gcol0 + tx;
            #pragma unroll
            for (int o = 0; o < CC; ++o) {
                float wih = fmaf(acc[r][o], g_[o], be[o]);
                float sg  = fast_sigmoid(wih);
                float den = fmaf(cmv[o], sg, vl[o]);
                float num = fmaf(tm[o] * vpre[r][o], __builtin_amdgcn_rcpf(den), wih * er[o]);
                float v   = fast_sigmoid(num);
                vpre[r][o] = v;
                out[((size_t)((b * TT + t) * CC + o)) * HWp + ob] = v;
            }
        }

        if (t < TT - 1) {
            __syncthreads();        // everyone done reading xs for this t
            stage_write(vb);        // vmcnt wait folded in by compiler
            __syncthreads();        // staged data visible
        }
    }
}

// ---------------- fused detection head + decode, all 3 scales ----------------
#define SMEM_F 18432   // max(768*24, 512*21)

extern "C" __global__ __launch_bounds__(512)
void head_fused_kernel(const float* __restrict__ y3, const float* __restrict__ w3, const float* __restrict__ b3,
                       const float* __restrict__ y2, const float* __restrict__ w2, const float* __restrict__ b2,
                       const float* __restrict__ y1, const float* __restrict__ w1, const float* __restrict__ b1,
                       float* __restrict__ det)
{
    __shared__ float smem[SMEM_F];

    const int bid = blockIdx.x;
    const float *y, *w, *bias;
    int Cin, f, lgf, lgchunks, row_off;
    float s;
    float aw0, aw1, aw2, ah0, ah1, ah2;
    int sb;

    if (bid < 512) {
        sb = bid;       y = y3; w = w3; bias = b3; Cin = 192; f = 64; lgf = 6; lgchunks = 6; s = 8.0f;  row_off = 0;
        aw0 = 10.f;  ah0 = 13.f;  aw1 = 16.f;  ah1 = 30.f;  aw2 = 33.f;  ah2 = 23.f;
    } else if (bid < 640) {
        sb = bid - 512; y = y2; w = w2; bias = b2; Cin = 384; f = 32; lgf = 5; lgchunks = 4; s = 16.0f; row_off = 12288;
        aw0 = 30.f;  ah0 = 61.f;  aw1 = 62.f;  ah1 = 45.f;  aw2 = 59.f;  ah2 = 119.f;
    } else {
        sb = bid - 640; y = y1; w = w1; bias = b1; Cin = 768; f = 16; lgf = 4; lgchunks = 2; s = 32.0f; row_off = 15360;
        aw0 = 116.f; ah0 = 90.f;  aw1 = 156.f; ah1 = 198.f; aw2 = 373.f; ah2 = 326.f;
    }

    const int n     = f * f;
    const int b     = sb >> lgchunks;
    const int chunk = sb & ((1 << lgchunks) - 1);

    const int tid  = threadIdx.x;
    const int lane = tid & 63;
    const int grp  = tid >> 6;          // 0..7

    // ---- stage wT (padded rows of 24) into LDS ----
    const int wtot = Cin * 21;
    for (int i = tid; i < wtot; i += 512) {
        int o = i / Cin;
        int c = i - o * Cin;
        smem[c * 24 + o] = w[i];
    }
    __syncthreads();

    const int G   = Cin >> 3;
    const int pix = (chunk << 6) + lane;

    float acc[21];
    #pragma unroll
    for (int o = 0; o < 21; ++o) acc[o] = 0.0f;

    const float* yp = y + ((size_t)b * Cin + (size_t)grp * G) * n + pix;
    const int wbase = grp * G * 24;

    #pragma unroll 4
    for (int c = 0; c < G; ++c) {
        float v = yp[(size_t)c * n];                     // coalesced
        const float* wr = &smem[wbase + c * 24];         // wave-uniform -> broadcast
        float4 q0 = *(const float4*)(wr);
        float4 q1 = *(const float4*)(wr + 4);
        float4 q2 = *(const float4*)(wr + 8);
        float4 q3 = *(const float4*)(wr + 12);
        float4 q4 = *(const float4*)(wr + 16);
        float  s20 = wr[20];
        float wv[21] = {q0.x,q0.y,q0.z,q0.w, q1.x,q1.y,q1.z,q1.w,
                        q2.x,q2.y,q2.z,q2.w, q3.x,q3.y,q3.z,q3.w,
                        q4.x,q4.y,q4.z,q4.w, s20};
        #pragma unroll
        for (int o = 0; o < 21; ++o) acc[o] = fmaf(v, wv[o], acc[o]);
    }
    __syncthreads();   // all reads of wT done; smem reused for reduction

    #pragma unroll
    for (int o = 0; o < 21; ++o) smem[tid * 21 + o] = acc[o];
    __syncthreads();

    if (tid < 64) {
        float r[21];
        #pragma unroll
        for (int o = 0; o < 21; ++o) r[o] = bias[o];
        #pragma unroll
        for (int g2 = 0; g2 < 8; ++g2) {
            const float* rp = &smem[(g2 * 64 + lane) * 21];
            #pragma unroll
            for (int o = 0; o < 21; ++o) r[o] += rp[o];
        }

        const int hy = pix >> lgf;
        const int hx = pix & (f - 1);
        const float inv = 1.0f / 512.0f;
        const float AW[3] = {aw0, aw1, aw2};
        const float AH[3] = {ah0, ah1, ah2};

        #pragma unroll
        for (int a = 0; a < 3; ++a) {
            const int row = row_off + pix * 3 + a;
            float* dp = det + ((size_t)b * 16128 + row) * 7;
            dp[0] = r[a];
            dp[1] = r[3 + a * 2];
            dp[2] = r[4 + a * 2];
            float txv = r[9  + a * 4];
            float tyv = r[10 + a * 4];
            float twv = r[11 + a * 4];
            float thv = r[12 + a * 4];
            float cx = (fast_sigmoid(txv) + (float)hx) * s;
            float cy = (fast_sigmoid(tyv) + (float)hy) * s;
            float bw = __expf(twv) * AW[a];
            float bh = __expf(thv) * AH[a];
            dp[3] = (cx - bw * 0.5f) * inv;
            dp[4] = (cy - bh * 0.5f) * inv;
            dp[5] = (cx + bw * 0.5f) * inv;
            dp[6] = (cy + bh * 0.5f) * inv;
        }
    }
}

extern "C" void kernel_launch(void* const* d_in, const int* in_sizes, int n_in,
                              void* d_out, int out_size, void* d_ws, size_t ws_size,
                              hipStream_t stream)
{
    const float* x     = (const float*)d_in[0];
    const float* y1    = (const float*)d_in[1];   // [8,768,16,16]
    const float* y2    = (const float*)d_in[2];   // [8,384,32,32]
    const float* y3    = (const float*)d_in[3];   // [8,192,64,64]
    const float* cw    = (const float*)d_in[4];
    const float* gamma = (const float*)d_in[5];
    const float* beta  = (const float*)d_in[6];
    const float* cm    = (const float*)d_in[7];
    const float* vleak = (const float*)d_in[8];
    const float* tau   = (const float*)d_in[9];
    const float* erev  = (const float*)d_in[10];
    const float* w1    = (const float*)d_in[11];
    const float* b1    = (const float*)d_in[12];
    const float* w2    = (const float*)d_in[13];
    const float* b2    = (const float*)d_in[14];
    const float* w3    = (const float*)d_in[15];
    const float* b3    = (const float*)d_in[16];

    float* out = (float*)d_out;
    float* det = out + (size_t)8 * TT * CC * HH * WW;   // 52,428,800

    dim3 cgrid(WW / CTW, HH / CTH, 8);     // 8 x 32 x 8
    conv_ltc_kernel<<<cgrid, 512, 0, stream>>>(x, cw, gamma, beta, cm, vleak, tau, erev, out);

    head_fused_kernel<<<dim3(672), 512, 0, stream>>>(y3, w3, b3, y2, w2, b2, y1, w1, b1, det);
}